// Round 7
// baseline (322.400 us; speedup 1.0000x reference)
//
#include <hip/hip_runtime.h>

#define NN 100000
#define NE 2400000
#define NB 391              // buckets of 256 dst nodes
#define CAP 6912            // per-bucket edge capacity (mean 6144, +9.8 sigma)

// ---------------- zero ideg + cur ----------------
__global__ void k_zero(int* __restrict__ ideg, int* __restrict__ cur) {
    int i = blockIdx.x * 256 + threadIdx.x;
    if (i < NN) ideg[i] = 0;
    if (i < NB) cur[i] = 0;
}

// ---------------- bin edges by dst-bucket (fixed bases) + count degrees ----------------
__global__ __launch_bounds__(512) void k_binscatter(const int* __restrict__ ei,
        int* __restrict__ cur, int* __restrict__ ideg, int* __restrict__ binned) {
    __shared__ int hist[NB], lbase[NB], myb[NB];
    __shared__ int sh[512];
    __shared__ int stage[4096];
    __shared__ unsigned short stageb[4096];
    __shared__ int tot;
    int tid = threadIdx.x;
    for (int i = tid; i < NB; i += 512) hist[i] = 0;
    __syncthreads();
    int e0 = blockIdx.x * 4096;
    int pk[8], bn[8];
    for (int k = 0; k < 8; ++k) {
        int e = e0 + k * 512 + tid;
        if (e < NE) {
            int s = ei[e], d = ei[NE + e];
            bn[k] = d >> 8;
            pk[k] = s | ((d & 255) << 17);
            atomicAdd(&hist[bn[k]], 1);
            atomicAdd(&ideg[d], 1);                  // per-node degree (global)
        } else bn[k] = -1;
    }
    __syncthreads();
    int v = (tid < NB) ? hist[tid] : 0;
    sh[tid] = v; __syncthreads();
    for (int off = 1; off < 512; off <<= 1) {
        int t = (tid >= off) ? sh[tid - off] : 0; __syncthreads();
        sh[tid] += t; __syncthreads();
    }
    if (tid < NB) lbase[tid] = sh[tid] - v;
    if (tid == 511) tot = sh[511];
    if (tid < NB && v > 0) myb[tid] = tid * CAP + atomicAdd(&cur[tid], v);
    __syncthreads();
    if (tid < NB) hist[tid] = 0;
    __syncthreads();
    for (int k = 0; k < 8; ++k) {
        if (bn[k] >= 0) {
            int r = atomicAdd(&hist[bn[k]], 1);
            int slot = lbase[bn[k]] + r;
            stage[slot] = pk[k];
            stageb[slot] = (unsigned short)bn[k];
        }
    }
    __syncthreads();
    int T = tot;
    for (int j = tid; j < T; j += 512) {
        int b = stageb[j];
        binned[myb[b] + (j - lbase[b])] = stage[j];
    }
}

// ---------------- dinv + prescaled xs from ideg ----------------
__global__ void k_prep(const int* __restrict__ ideg, const float* __restrict__ x,
                       float* __restrict__ dinv, float2* __restrict__ xs) {
    int i = blockIdx.x * 256 + threadIdx.x;
    if (i < NN) {
        float di = rsqrtf((float)(ideg[i] + 1));     // +1 self-loop
        dinv[i] = di;
        float2 xv = ((const float2*)x)[i];
        xs[i] = make_float2(di * xv.x, di * xv.y);
    }
}

// ---------------- build csr + FUSED layer-1 gather + W1 epilogue ----------------
__global__ __launch_bounds__(256) void k_build_csr(const int* __restrict__ binned,
        const int* __restrict__ cur, const int* __restrict__ ideg,
        const float2* __restrict__ xs, const float* __restrict__ dinv,
        const float* __restrict__ W, const float* __restrict__ bias,
        int* __restrict__ rsp, int* __restrict__ csr, float* __restrict__ Y) {
    __shared__ int sh[256], cur2[256];
    __shared__ float accx[256], accy[256];
    int tid = threadIdx.x, b = blockIdx.x;
    int base = b * CAP;
    int n = cur[b];
    int node = (b << 8) + tid;
    int deg = (node < NN) ? ideg[node] : 0;
    sh[tid] = deg; __syncthreads();
    for (int off = 1; off < 256; off <<= 1) {
        int t = (tid >= off) ? sh[tid - off] : 0; __syncthreads();
        sh[tid] += t; __syncthreads();
    }
    int start = sh[tid] - deg;
    if (node < NN) rsp[node] = ((base + start) << 8) | deg;   // packed
    cur2[tid] = start;
    accx[tid] = 0.f; accy[tid] = 0.f;
    __syncthreads();
    for (int j = tid; j < n; j += 256) {
        int w = binned[base + j];
        int s = w & 0x1FFFF, dl = (w >> 17) & 255;
        int p = atomicAdd(&cur2[dl], 1);
        csr[base + p] = s;
        float2 xv = xs[s];                    // dinv[s]-prescaled, L2-resident
        atomicAdd(&accx[dl], xv.x);
        atomicAdd(&accy[dl], xv.y);
    }
    __syncthreads();
    if (node < NN) {
        float di = dinv[node];
        float2 xn = xs[node];                 // self-loop term
        float a0 = di * (accx[tid] + xn.x);
        float a1 = di * (accy[tid] + xn.y);
        const float4* W4 = (const float4*)W;
        const float4* B4 = (const float4*)bias;
        float4* yrow = (float4*)(Y + (node << 5));
#pragma unroll
        for (int q = 0; q < 8; ++q) {
            float4 w0 = W4[q], w1 = W4[8 + q], bb = B4[q];
            float4 r;
            r.x = a0 * w0.x + a1 * w1.x + bb.x;
            r.y = a0 * w0.y + a1 * w1.y + bb.y;
            r.z = a0 * w0.z + a1 * w1.z + bb.z;
            r.w = a0 * w0.w + a1 * w1.w + bb.w;
            r.x = di * (r.x > 0.f ? r.x : 0.f);
            r.y = di * (r.y > 0.f ? r.y : 0.f);
            r.z = di * (r.z > 0.f ? r.z : 0.f);
            r.w = di * (r.w > 0.f ? r.w : 0.f);
            yrow[q] = r;                      // Y = dinv * relu(...), prescaled
        }
    }
}

// ---------------- width-32 gather + FUSED W2 epilogue + FUSED W3 -> h3 ----------------
__global__ __launch_bounds__(256) void k_gather32f(const float* __restrict__ Ys,
        const int* __restrict__ rsp, const int* __restrict__ csr,
        const float* __restrict__ dinv, const float* __restrict__ W,
        const float* __restrict__ bias, const float* __restrict__ W3,
        float* __restrict__ h3) {
    __shared__ float accS[256];               // 8 nodes x 32
    __shared__ float Ws[1024];
    for (int j = threadIdx.x; j < 1024; j += 256) Ws[j] = W[j];
    int node = blockIdx.x * 8 + (threadIdx.x >> 5);
    int f = threadIdx.x & 31;
    float acc = 0.f, di = 0.f;
    if (node < NN) {
        int r = rsp[node];
        int beg = r >> 8, end = beg + (r & 255);
        acc = Ys[(node << 5) + f];            // self-loop (prescaled)
        int e = beg;
        for (; e + 4 <= end; e += 4) {
            int s0 = csr[e], s1 = csr[e + 1], s2 = csr[e + 2], s3 = csr[e + 3];
            float v0 = Ys[(s0 << 5) + f], v1 = Ys[(s1 << 5) + f];
            float v2 = Ys[(s2 << 5) + f], v3 = Ys[(s3 << 5) + f];
            acc += (v0 + v1) + (v2 + v3);
        }
        for (; e < end; ++e) acc += Ys[(csr[e] << 5) + f];
        di = dinv[node];
    }
    accS[threadIdx.x] = di * acc;             // agg2 = di * (sum + self)
    __syncthreads();                          // also covers Ws
    if (node < NN) {
        int n = threadIdx.x >> 5;
        float sum = bias[f];
#pragma unroll
        for (int k = 0; k < 32; ++k) sum += accS[(n << 5) + k] * Ws[(k << 5) + f];
        float h2 = sum > 0.f ? sum : 0.f;
        float v = di * h2 * W3[f];            // prescaled h3 contribution
#pragma unroll
        for (int off = 16; off > 0; off >>= 1) v += __shfl_down(v, off, 32);
        if (f == 0) h3[node] = v;
    }
}

// ---------------- width-1 gather -> out ----------------
__global__ __launch_bounds__(256) void k_gather_out(const float* __restrict__ hs,
        const int* __restrict__ rsp, const int* __restrict__ csr,
        const float* __restrict__ dinv, const float* __restrict__ bias,
        float* __restrict__ out) {
    int node = blockIdx.x * 256 + threadIdx.x;
    if (node >= NN) return;
    int r = rsp[node];
    int beg = r >> 8, end = beg + (r & 255);
    float acc = hs[node];
    int e = beg;
    for (; e + 4 <= end; e += 4) {
        int s0 = csr[e], s1 = csr[e + 1], s2 = csr[e + 2], s3 = csr[e + 3];
        acc += (hs[s0] + hs[s1]) + (hs[s2] + hs[s3]);
    }
    for (; e < end; ++e) acc += hs[csr[e]];
    out[node] = dinv[node] * acc + bias[0];
}

extern "C" void kernel_launch(void* const* d_in, const int* in_sizes, int n_in,
                              void* d_out, int out_size, void* d_ws, size_t ws_size,
                              hipStream_t stream) {
    const float* x  = (const float*)d_in[0];
    const int*   ei = (const int*)d_in[1];   // [2, NE] int32
    const float* W1 = (const float*)d_in[2];
    const float* b1 = (const float*)d_in[3];
    const float* W2 = (const float*)d_in[4];
    const float* b2 = (const float*)d_in[5];
    const float* W3 = (const float*)d_in[6];
    const float* b3 = (const float*)d_in[7];
    float* out = (float*)d_out;

    char* w = (char*)d_ws;
    float2* xs   = (float2*)w;  w += NN * 8;            // 8B-aligned first
    int*   ideg  = (int*)w;     w += NN * 4;
    int*   cur   = (int*)w;     w += NB * 4;
    int*   rsp   = (int*)w;     w += NN * 4;
    float* dinv  = (float*)w;   w += NN * 4;
    int*   binned = (int*)w;    w += NB * CAP * 4;      // 10.8 MB
    int*   csr   = (int*)w;     w += NB * CAP * 4;      // 10.8 MB
    float* Y     = (float*)w;   w += NN * 32 * 4;       // 12.8 MB
    float* h3    = (float*)w;   w += NN * 4;

    const int G_E4K = (NE + 4095) / 4096;   // 586
    const int G_N   = (NN + 255) / 256;     // 391
    const int G_G   = (NN + 7) / 8;         // 12500

    k_zero<<<G_N, 256, 0, stream>>>(ideg, cur);
    k_binscatter<<<G_E4K, 512, 0, stream>>>(ei, cur, ideg, binned);
    k_prep<<<G_N, 256, 0, stream>>>(ideg, x, dinv, xs);
    k_build_csr<<<NB, 256, 0, stream>>>(binned, cur, ideg, xs, dinv, W1, b1,
                                        rsp, csr, Y);
    k_gather32f<<<G_G, 256, 0, stream>>>(Y, rsp, csr, dinv, W2, b2, W3, h3);
    k_gather_out<<<G_N, 256, 0, stream>>>(h3, rsp, csr, dinv, b3, out);
}

// Round 8
// 243.470 us; speedup vs baseline: 1.3242x; 1.3242x over previous
//
#include <hip/hip_runtime.h>

#define NN 100000
#define NE 2400000
#define NB 391              // buckets of 256 dst nodes
#define CAP 6912            // per-bucket edge capacity (mean 6144, +9.8 sigma)

// ---------------- zero bucket cursors ----------------
__global__ void k_zero(int* __restrict__ cur) {
    int i = threadIdx.x;
    if (i < NB) cur[i] = 0;
}

// ---------------- bin edges by dst-bucket (fixed bases), single rank round ----------------
__global__ __launch_bounds__(512) void k_binscatter(const int* __restrict__ ei,
        int* __restrict__ cur, int* __restrict__ binned) {
    __shared__ int hist[NB], lbase[NB], myb[NB];
    __shared__ int sh[512];
    __shared__ int stage[4096];
    __shared__ unsigned short stageb[4096];
    __shared__ int tot;
    int tid = threadIdx.x;
    for (int i = tid; i < NB; i += 512) hist[i] = 0;
    __syncthreads();
    int e0 = blockIdx.x * 4096;
    int pk[8], bn[8], rk[8];
    for (int k = 0; k < 8; ++k) {
        int e = e0 + k * 512 + tid;
        if (e < NE) {
            int s = ei[e], d = ei[NE + e];
            bn[k] = d >> 8;
            pk[k] = s | ((d & 255) << 17);
            rk[k] = atomicAdd(&hist[bn[k]], 1);      // rank == final count
        } else bn[k] = -1;
    }
    __syncthreads();
    int v = (tid < NB) ? hist[tid] : 0;
    sh[tid] = v; __syncthreads();
    for (int off = 1; off < 512; off <<= 1) {
        int t = (tid >= off) ? sh[tid - off] : 0; __syncthreads();
        sh[tid] += t; __syncthreads();
    }
    if (tid < NB) lbase[tid] = sh[tid] - v;
    if (tid == 511) tot = sh[511];
    if (tid < NB && v > 0) myb[tid] = tid * CAP + atomicAdd(&cur[tid], v);
    __syncthreads();
    for (int k = 0; k < 8; ++k) {
        if (bn[k] >= 0) {
            int slot = lbase[bn[k]] + rk[k];
            stage[slot] = pk[k];
            stageb[slot] = (unsigned short)bn[k];
        }
    }
    __syncthreads();
    int T = tot;
    for (int j = tid; j < T; j += 512) {
        int b = stageb[j];
        binned[myb[b] + (j - lbase[b])] = stage[j];
    }
}

// ---------------- per-bucket degree count -> rsp, dinv, prescaled xs ----------------
__global__ __launch_bounds__(256) void k_csr_count(const int* __restrict__ binned,
        const int* __restrict__ cur, const float* __restrict__ x,
        int* __restrict__ rsp, float* __restrict__ dinv, float2* __restrict__ xs) {
    __shared__ int cnt[256], sh[256];
    int tid = threadIdx.x, b = blockIdx.x;
    int base = b * CAP, n = cur[b];
    cnt[tid] = 0;
    __syncthreads();
    for (int j = tid; j < n; j += 256)
        atomicAdd(&cnt[(binned[base + j] >> 17) & 255], 1);
    __syncthreads();
    int v = cnt[tid];
    sh[tid] = v; __syncthreads();
    for (int off = 1; off < 256; off <<= 1) {
        int t = (tid >= off) ? sh[tid - off] : 0; __syncthreads();
        sh[tid] += t; __syncthreads();
    }
    int node = (b << 8) + tid;
    if (node < NN) {
        rsp[node] = ((base + sh[tid] - v) << 8) | v;     // packed start|deg
        float di = rsqrtf((float)(v + 1));               // +1 self-loop
        dinv[node] = di;
        float2 xv = ((const float2*)x)[node];
        xs[node] = make_float2(di * xv.x, di * xv.y);
    }
}

// ---------------- csr placement + FUSED layer-1 gather + W1 epilogue ----------------
__global__ __launch_bounds__(256) void k_csr_place(const int* __restrict__ binned,
        const int* __restrict__ cur, const int* __restrict__ rsp,
        const float2* __restrict__ xs, const float* __restrict__ dinv,
        const float* __restrict__ W, const float* __restrict__ bias,
        int* __restrict__ csr, float* __restrict__ Y) {
    __shared__ int cur2[256];
    __shared__ float accx[256], accy[256];
    int tid = threadIdx.x, b = blockIdx.x;
    int base = b * CAP, n = cur[b];
    int node = (b << 8) + tid;
    cur2[tid] = (node < NN) ? ((rsp[node] >> 8) - base) : 0;
    accx[tid] = 0.f; accy[tid] = 0.f;
    __syncthreads();
    for (int j = tid; j < n; j += 256) {
        int w = binned[base + j];
        int s = w & 0x1FFFF, dl = (w >> 17) & 255;
        int p = atomicAdd(&cur2[dl], 1);
        csr[base + p] = s;
        float2 xv = xs[s];                    // dinv[s]-prescaled, L2-resident
        atomicAdd(&accx[dl], xv.x);
        atomicAdd(&accy[dl], xv.y);
    }
    __syncthreads();
    if (node < NN) {
        float di = dinv[node];
        float2 xn = xs[node];                 // self-loop term
        float a0 = di * (accx[tid] + xn.x);
        float a1 = di * (accy[tid] + xn.y);
        const float4* W4 = (const float4*)W;
        const float4* B4 = (const float4*)bias;
        float4* yrow = (float4*)(Y + (node << 5));
#pragma unroll
        for (int q = 0; q < 8; ++q) {
            float4 w0 = W4[q], w1 = W4[8 + q], bb = B4[q];
            float4 r;
            r.x = a0 * w0.x + a1 * w1.x + bb.x;
            r.y = a0 * w0.y + a1 * w1.y + bb.y;
            r.z = a0 * w0.z + a1 * w1.z + bb.z;
            r.w = a0 * w0.w + a1 * w1.w + bb.w;
            r.x = di * (r.x > 0.f ? r.x : 0.f);
            r.y = di * (r.y > 0.f ? r.y : 0.f);
            r.z = di * (r.z > 0.f ? r.z : 0.f);
            r.w = di * (r.w > 0.f ? r.w : 0.f);
            yrow[q] = r;                      // Y = dinv * relu(...), prescaled
        }
    }
}

// ---------------- width-32 gather + FUSED W2 epilogue + FUSED W3 -> h3 ----------------
__global__ __launch_bounds__(256) void k_gather32f(const float* __restrict__ Ys,
        const int* __restrict__ rsp, const int* __restrict__ csr,
        const float* __restrict__ dinv, const float* __restrict__ W,
        const float* __restrict__ bias, const float* __restrict__ W3,
        float* __restrict__ h3) {
    __shared__ float accS[256];               // 8 nodes x 32
    __shared__ float Ws[1024];
    for (int j = threadIdx.x; j < 1024; j += 256) Ws[j] = W[j];
    int node = blockIdx.x * 8 + (threadIdx.x >> 5);
    int f = threadIdx.x & 31;
    float acc = 0.f, di = 0.f;
    if (node < NN) {
        int r = rsp[node];
        int beg = r >> 8, end = beg + (r & 255);
        acc = Ys[(node << 5) + f];            // self-loop (prescaled)
        int e = beg;
        for (; e + 4 <= end; e += 4) {
            int s0 = csr[e], s1 = csr[e + 1], s2 = csr[e + 2], s3 = csr[e + 3];
            float v0 = Ys[(s0 << 5) + f], v1 = Ys[(s1 << 5) + f];
            float v2 = Ys[(s2 << 5) + f], v3 = Ys[(s3 << 5) + f];
            acc += (v0 + v1) + (v2 + v3);
        }
        for (; e < end; ++e) acc += Ys[(csr[e] << 5) + f];
        di = dinv[node];
    }
    accS[threadIdx.x] = di * acc;             // agg2 = di * (sum + self)
    __syncthreads();                          // also covers Ws
    if (node < NN) {
        int n = threadIdx.x >> 5;
        float sum = bias[f];
#pragma unroll
        for (int k = 0; k < 32; ++k) sum += accS[(n << 5) + k] * Ws[(k << 5) + f];
        float h2 = sum > 0.f ? sum : 0.f;
        float v = di * h2 * W3[f];            // prescaled h3 contribution
#pragma unroll
        for (int off = 16; off > 0; off >>= 1) v += __shfl_down(v, off, 32);
        if (f == 0) h3[node] = v;
    }
}

// ---------------- width-1 gather -> out ----------------
__global__ __launch_bounds__(256) void k_gather_out(const float* __restrict__ hs,
        const int* __restrict__ rsp, const int* __restrict__ csr,
        const float* __restrict__ dinv, const float* __restrict__ bias,
        float* __restrict__ out) {
    int node = blockIdx.x * 256 + threadIdx.x;
    if (node >= NN) return;
    int r = rsp[node];
    int beg = r >> 8, end = beg + (r & 255);
    float acc = hs[node];
    int e = beg;
    for (; e + 4 <= end; e += 4) {
        int s0 = csr[e], s1 = csr[e + 1], s2 = csr[e + 2], s3 = csr[e + 3];
        acc += (hs[s0] + hs[s1]) + (hs[s2] + hs[s3]);
    }
    for (; e < end; ++e) acc += hs[csr[e]];
    out[node] = dinv[node] * acc + bias[0];
}

extern "C" void kernel_launch(void* const* d_in, const int* in_sizes, int n_in,
                              void* d_out, int out_size, void* d_ws, size_t ws_size,
                              hipStream_t stream) {
    const float* x  = (const float*)d_in[0];
    const int*   ei = (const int*)d_in[1];   // [2, NE] int32
    const float* W1 = (const float*)d_in[2];
    const float* b1 = (const float*)d_in[3];
    const float* W2 = (const float*)d_in[4];
    const float* b2 = (const float*)d_in[5];
    const float* W3 = (const float*)d_in[6];
    const float* b3 = (const float*)d_in[7];
    float* out = (float*)d_out;

    char* w = (char*)d_ws;
    float2* xs    = (float2*)w; w += NN * 8;            // 8B-aligned first
    int*   cur    = (int*)w;    w += NB * 4;
    int*   rsp    = (int*)w;    w += NN * 4;
    float* dinv   = (float*)w;  w += NN * 4;
    int*   binned = (int*)w;    w += NB * CAP * 4;      // 10.8 MB
    int*   csr    = (int*)w;    w += NB * CAP * 4;      // 10.8 MB
    float* Y      = (float*)w;  w += NN * 32 * 4;       // 12.8 MB
    float* h3     = (float*)w;  w += NN * 4;

    const int G_E4K = (NE + 4095) / 4096;   // 586
    const int G_N   = (NN + 255) / 256;     // 391
    const int G_G   = (NN + 7) / 8;         // 12500

    k_zero<<<1, 512, 0, stream>>>(cur);
    k_binscatter<<<G_E4K, 512, 0, stream>>>(ei, cur, binned);
    k_csr_count<<<NB, 256, 0, stream>>>(binned, cur, x, rsp, dinv, xs);
    k_csr_place<<<NB, 256, 0, stream>>>(binned, cur, rsp, xs, dinv, W1, b1, csr, Y);
    k_gather32f<<<G_G, 256, 0, stream>>>(Y, rsp, csr, dinv, W2, b2, W3, h3);
    k_gather_out<<<G_N, 256, 0, stream>>>(h3, rsp, csr, dinv, b3, out);
}

// Round 9
// 220.825 us; speedup vs baseline: 1.4600x; 1.1025x over previous
//
#include <hip/hip_runtime.h>

#define NN 100000
#define NE 2400000
#define NB 391              // buckets of 256 dst nodes
#define CAP 6912            // per-bucket edge capacity (mean 6144, +9.8 sigma)

// ---------------- zero bucket cursors ----------------
__global__ void k_zero(int* __restrict__ cur) {
    int i = threadIdx.x;
    if (i < NB) cur[i] = 0;
}

// ---------------- bin edges by dst-bucket (fixed bases), single rank round ----------------
__global__ __launch_bounds__(512) void k_binscatter(const int* __restrict__ ei,
        int* __restrict__ cur, int* __restrict__ binned) {
    __shared__ int hist[NB], lbase[NB], myb[NB];
    __shared__ int sh[512];
    __shared__ int stage[4096];
    __shared__ unsigned short stageb[4096];
    __shared__ int tot;
    int tid = threadIdx.x;
    for (int i = tid; i < NB; i += 512) hist[i] = 0;
    __syncthreads();
    int e0 = blockIdx.x * 4096;
    int pk[8], bn[8], rk[8];
    for (int k = 0; k < 8; ++k) {
        int e = e0 + k * 512 + tid;
        if (e < NE) {
            int s = ei[e], d = ei[NE + e];
            bn[k] = d >> 8;
            pk[k] = s | ((d & 255) << 17);
            rk[k] = atomicAdd(&hist[bn[k]], 1);      // rank == final count
        } else bn[k] = -1;
    }
    __syncthreads();
    int v = (tid < NB) ? hist[tid] : 0;
    sh[tid] = v; __syncthreads();
    for (int off = 1; off < 512; off <<= 1) {
        int t = (tid >= off) ? sh[tid - off] : 0; __syncthreads();
        sh[tid] += t; __syncthreads();
    }
    if (tid < NB) lbase[tid] = sh[tid] - v;
    if (tid == 511) tot = sh[511];
    if (tid < NB && v > 0) myb[tid] = tid * CAP + atomicAdd(&cur[tid], v);
    __syncthreads();
    for (int k = 0; k < 8; ++k) {
        if (bn[k] >= 0) {
            int slot = lbase[bn[k]] + rk[k];
            stage[slot] = pk[k];
            stageb[slot] = (unsigned short)bn[k];
        }
    }
    __syncthreads();
    int T = tot;
    for (int j = tid; j < T; j += 512) {
        int b = stageb[j];
        binned[myb[b] + (j - lbase[b])] = stage[j];
    }
}

// ---------------- per-bucket degree count -> rsp, dinv, prescaled xs ----------------
__global__ __launch_bounds__(256) void k_csr_count(const int* __restrict__ binned,
        const int* __restrict__ cur, const float* __restrict__ x,
        int* __restrict__ rsp, float* __restrict__ dinv, float2* __restrict__ xs) {
    __shared__ int cnt[256], sh[256];
    int tid = threadIdx.x, b = blockIdx.x;
    int base = b * CAP, n = cur[b];
    cnt[tid] = 0;
    __syncthreads();
    for (int j = tid; j < n; j += 256)
        atomicAdd(&cnt[(binned[base + j] >> 17) & 255], 1);
    __syncthreads();
    int v = cnt[tid];
    sh[tid] = v; __syncthreads();
    for (int off = 1; off < 256; off <<= 1) {
        int t = (tid >= off) ? sh[tid - off] : 0; __syncthreads();
        sh[tid] += t; __syncthreads();
    }
    int node = (b << 8) + tid;
    if (node < NN) {
        rsp[node] = ((base + sh[tid] - v) << 8) | v;     // packed start|deg
        float di = rsqrtf((float)(v + 1));               // +1 self-loop
        dinv[node] = di;
        float2 xv = ((const float2*)x)[node];
        xs[node] = make_float2(di * xv.x, di * xv.y);
    }
}

// ---------------- csr placement + layer-1 aggregate -> At = (a0, a1, dinv) ----------------
__global__ __launch_bounds__(256) void k_csr_place(const int* __restrict__ binned,
        const int* __restrict__ cur, const int* __restrict__ rsp,
        const float2* __restrict__ xs, const float* __restrict__ dinv,
        int* __restrict__ csr, float4* __restrict__ At) {
    __shared__ int cur2[256];
    __shared__ float accx[256], accy[256];
    int tid = threadIdx.x, b = blockIdx.x;
    int base = b * CAP, n = cur[b];
    int node = (b << 8) + tid;
    cur2[tid] = (node < NN) ? ((rsp[node] >> 8) - base) : 0;
    accx[tid] = 0.f; accy[tid] = 0.f;
    __syncthreads();
    for (int j = tid; j < n; j += 256) {
        int w = binned[base + j];
        int s = w & 0x1FFFF, dl = (w >> 17) & 255;
        int p = atomicAdd(&cur2[dl], 1);
        csr[base + p] = s;
        float2 xv = xs[s];                    // dinv[s]-prescaled, L2-resident
        atomicAdd(&accx[dl], xv.x);
        atomicAdd(&accy[dl], xv.y);
    }
    __syncthreads();
    if (node < NN) {
        float di = dinv[node];
        float2 xn = xs[node];                 // self-loop term
        // a0,a1 = dinv[node] * (sum of prescaled neighbors + prescaled self)
        At[node] = make_float4(di * (accx[tid] + xn.x),
                               di * (accy[tid] + xn.y), di, 0.f);
    }
}

// ---------------- layer-2 gather with ON-THE-FLY h1 + W2 epilogue + W3 -> h3 ----------------
__global__ __launch_bounds__(256) void k_gather_fly(const float4* __restrict__ At,
        const int* __restrict__ rsp, const int* __restrict__ csr,
        const float* __restrict__ W1, const float* __restrict__ b1,
        const float* __restrict__ W2, const float* __restrict__ b2,
        const float* __restrict__ W3, float* __restrict__ h3) {
    __shared__ float accS[256];               // 8 nodes x 32
    __shared__ float Ws[1024];
    for (int j = threadIdx.x; j < 1024; j += 256) Ws[j] = W2[j];
    int node = blockIdx.x * 8 + (threadIdx.x >> 5);
    int f = threadIdx.x & 31;
    float w0f = W1[f], w1f = W1[32 + f], bf = b1[f];
    float acc = 0.f, di = 0.f;
    if (node < NN) {
        float4 an = At[node];
        di = an.z;
        float vs = fmaf(an.y, w1f, fmaf(an.x, w0f, bf));
        vs = vs > 0.f ? vs : 0.f;
        acc = an.z * vs;                      // self-loop: Y[node][f]
        int r = rsp[node];
        int beg = r >> 8, deg = r & 255;
        for (int b0 = 0; b0 < deg; b0 += 32) {
            int mye = b0 + f;
            float4 a = make_float4(0.f, 0.f, 0.f, 0.f);
            if (mye < deg) a = At[csr[beg + mye]];   // 32 loads in flight
            int m = deg - b0; if (m > 32) m = 32;
#pragma unroll 4
            for (int j = 0; j < m; ++j) {
                float a0 = __shfl(a.x, j, 32);       // broadcast edge j's state
                float a1 = __shfl(a.y, j, 32);
                float az = __shfl(a.z, j, 32);
                float v = fmaf(a1, w1f, fmaf(a0, w0f, bf));
                v = v > 0.f ? v : 0.f;               // h1[s][f]
                acc = fmaf(az, v, acc);              // += dinv[s]*h1[s][f]
            }
        }
    }
    accS[threadIdx.x] = di * acc;             // agg2 = di * (sum + self)
    __syncthreads();                          // also covers Ws
    if (node < NN) {
        int n = threadIdx.x >> 5;
        float sum = b2[f];
#pragma unroll
        for (int k = 0; k < 32; ++k) sum += accS[(n << 5) + k] * Ws[(k << 5) + f];
        float h2 = sum > 0.f ? sum : 0.f;
        float v = di * h2 * W3[f];            // prescaled h3 contribution
#pragma unroll
        for (int off = 16; off > 0; off >>= 1) v += __shfl_down(v, off, 32);
        if (f == 0) h3[node] = v;
    }
}

// ---------------- width-1 gather -> out ----------------
__global__ __launch_bounds__(256) void k_gather_out(const float* __restrict__ hs,
        const int* __restrict__ rsp, const int* __restrict__ csr,
        const float* __restrict__ dinv, const float* __restrict__ bias,
        float* __restrict__ out) {
    int node = blockIdx.x * 256 + threadIdx.x;
    if (node >= NN) return;
    int r = rsp[node];
    int beg = r >> 8, end = beg + (r & 255);
    float acc = hs[node];
    int e = beg;
    for (; e + 4 <= end; e += 4) {
        int s0 = csr[e], s1 = csr[e + 1], s2 = csr[e + 2], s3 = csr[e + 3];
        acc += (hs[s0] + hs[s1]) + (hs[s2] + hs[s3]);
    }
    for (; e < end; ++e) acc += hs[csr[e]];
    out[node] = dinv[node] * acc + bias[0];
}

extern "C" void kernel_launch(void* const* d_in, const int* in_sizes, int n_in,
                              void* d_out, int out_size, void* d_ws, size_t ws_size,
                              hipStream_t stream) {
    const float* x  = (const float*)d_in[0];
    const int*   ei = (const int*)d_in[1];   // [2, NE] int32
    const float* W1 = (const float*)d_in[2];
    const float* b1 = (const float*)d_in[3];
    const float* W2 = (const float*)d_in[4];
    const float* b2 = (const float*)d_in[5];
    const float* W3 = (const float*)d_in[6];
    const float* b3 = (const float*)d_in[7];
    float* out = (float*)d_out;

    char* w = (char*)d_ws;
    float4* At    = (float4*)w; w += NN * 16;           // 16B-aligned first, 1.6 MB
    float2* xs    = (float2*)w; w += NN * 8;
    int*   cur    = (int*)w;    w += NB * 4;
    int*   rsp    = (int*)w;    w += NN * 4;
    float* dinv   = (float*)w;  w += NN * 4;
    int*   binned = (int*)w;    w += NB * CAP * 4;      // 10.8 MB
    int*   csr    = (int*)w;    w += NB * CAP * 4;      // 10.8 MB
    float* h3     = (float*)w;  w += NN * 4;

    const int G_E4K = (NE + 4095) / 4096;   // 586
    const int G_N   = (NN + 255) / 256;     // 391
    const int G_G   = (NN + 7) / 8;         // 12500

    k_zero<<<1, 512, 0, stream>>>(cur);
    k_binscatter<<<G_E4K, 512, 0, stream>>>(ei, cur, binned);
    k_csr_count<<<NB, 256, 0, stream>>>(binned, cur, x, rsp, dinv, xs);
    k_csr_place<<<NB, 256, 0, stream>>>(binned, cur, rsp, xs, dinv, csr, At);
    k_gather_fly<<<G_G, 256, 0, stream>>>(At, rsp, csr, W1, b1, W2, b2, W3, h3);
    k_gather_out<<<G_N, 256, 0, stream>>>(h3, rsp, csr, dinv, b3, out);
}

// Round 10
// 220.319 us; speedup vs baseline: 1.4633x; 1.0023x over previous
//
#include <hip/hip_runtime.h>

#define NN 100000
#define NE 2400000
#define NB 391              // buckets of 256 dst nodes
#define CAP 6912            // per-bucket edge capacity (mean 6144, +9.8 sigma)

// ---------------- bin edges by dst-bucket (fixed bases), single rank round ----------------
__global__ __launch_bounds__(512) void k_binscatter(const int* __restrict__ ei,
        int* __restrict__ cur, int* __restrict__ binned) {
    __shared__ int hist[NB], lbase[NB], myb[NB];
    __shared__ int sh[512];
    __shared__ int stage[4096];
    __shared__ unsigned short stageb[4096];
    __shared__ int tot;
    int tid = threadIdx.x;
    for (int i = tid; i < NB; i += 512) hist[i] = 0;
    __syncthreads();
    int e0 = blockIdx.x * 4096;
    int pk[8], bn[8], rk[8];
    for (int k = 0; k < 8; ++k) {
        int e = e0 + k * 512 + tid;
        if (e < NE) {
            int s = ei[e], d = ei[NE + e];
            bn[k] = d >> 8;
            pk[k] = s | ((d & 255) << 17);
            rk[k] = atomicAdd(&hist[bn[k]], 1);      // rank == final count
        } else bn[k] = -1;
    }
    __syncthreads();
    int v = (tid < NB) ? hist[tid] : 0;
    sh[tid] = v; __syncthreads();
    for (int off = 1; off < 512; off <<= 1) {
        int t = (tid >= off) ? sh[tid - off] : 0; __syncthreads();
        sh[tid] += t; __syncthreads();
    }
    if (tid < NB) lbase[tid] = sh[tid] - v;
    if (tid == 511) tot = sh[511];
    if (tid < NB && v > 0) myb[tid] = tid * CAP + atomicAdd(&cur[tid], v);
    __syncthreads();
    for (int k = 0; k < 8; ++k) {
        if (bn[k] >= 0) {
            int slot = lbase[bn[k]] + rk[k];
            stage[slot] = pk[k];
            stageb[slot] = (unsigned short)bn[k];
        }
    }
    __syncthreads();
    int T = tot;
    for (int j = tid; j < T; j += 512) {
        int b = stageb[j];
        binned[myb[b] + (j - lbase[b])] = stage[j];
    }
}

// ---------------- per-bucket degree count -> rsp, dinv, prescaled xs ----------------
__global__ __launch_bounds__(256) void k_csr_count(const int* __restrict__ binned,
        const int* __restrict__ cur, const float* __restrict__ x,
        int* __restrict__ rsp, float* __restrict__ dinv, float2* __restrict__ xs) {
    __shared__ int cnt[256], sh[256];
    int tid = threadIdx.x, b = blockIdx.x;
    int base = b * CAP, n = cur[b];
    cnt[tid] = 0;
    __syncthreads();
    for (int j = tid; j < n; j += 256)
        atomicAdd(&cnt[(binned[base + j] >> 17) & 255], 1);
    __syncthreads();
    int v = cnt[tid];
    sh[tid] = v; __syncthreads();
    for (int off = 1; off < 256; off <<= 1) {
        int t = (tid >= off) ? sh[tid - off] : 0; __syncthreads();
        sh[tid] += t; __syncthreads();
    }
    int node = (b << 8) + tid;
    if (node < NN) {
        rsp[node] = ((base + sh[tid] - v) << 8) | v;     // packed start|deg
        float di = rsqrtf((float)(v + 1));               // +1 self-loop
        dinv[node] = di;
        float2 xv = ((const float2*)x)[node];
        xs[node] = make_float2(di * xv.x, di * xv.y);
    }
}

// ---------------- csr placement, then per-node register walk -> At ----------------
__global__ __launch_bounds__(256) void k_csr_place(const int* __restrict__ binned,
        const int* __restrict__ cur, const int* __restrict__ rsp,
        const float2* __restrict__ xs, const float* __restrict__ dinv,
        int* __restrict__ csr, float4* __restrict__ At) {
    __shared__ int cur2[256];
    int tid = threadIdx.x, b = blockIdx.x;
    int base = b * CAP, n = cur[b];
    int node = (b << 8) + tid;
    int rp = (node < NN) ? rsp[node] : 0;
    cur2[tid] = (node < NN) ? ((rp >> 8) - base) : 0;
    __syncthreads();
    for (int j = tid; j < n; j += 256) {
        int w = binned[base + j];
        int s = w & 0x1FFFF, dl = (w >> 17) & 255;
        int p = atomicAdd(&cur2[dl], 1);
        csr[base + p] = s;                    // only 1 LDS atomic per edge
    }
    __syncthreads();                          // csr slice complete (L2-hot)
    if (node < NN) {
        int beg = rp >> 8, deg = rp & 255;
        float ax = 0.f, ay = 0.f;
        int e = beg, end = beg + deg;
        for (; e + 4 <= end; e += 4) {
            int s0 = csr[e], s1 = csr[e + 1], s2 = csr[e + 2], s3 = csr[e + 3];
            float2 v0 = xs[s0], v1 = xs[s1], v2 = xs[s2], v3 = xs[s3];
            ax += (v0.x + v1.x) + (v2.x + v3.x);
            ay += (v0.y + v1.y) + (v2.y + v3.y);
        }
        for (; e < end; ++e) { float2 vv = xs[csr[e]]; ax += vv.x; ay += vv.y; }
        float di = dinv[node];
        float2 xn = xs[node];                 // self-loop term
        At[node] = make_float4(di * (ax + xn.x), di * (ay + xn.y), di, 0.f);
    }
}

// ---------------- layer-2 gather, on-the-fly h1, W2+W3 epilogue, NO barrier ----------------
__global__ __launch_bounds__(256) void k_gather_fly(const float4* __restrict__ At,
        const int* __restrict__ rsp, const int* __restrict__ csr,
        const float* __restrict__ W1, const float* __restrict__ b1,
        const float* __restrict__ W2, const float* __restrict__ b2,
        const float* __restrict__ W3, float* __restrict__ h3) {
    __shared__ float Ws[1024];
    __shared__ float accS[256];
    int tid = threadIdx.x;
    int lane = tid & 63;
    for (int j = lane; j < 1024; j += 64) Ws[j] = W2[j];  // per-wave redundant (benign race)
    int node = blockIdx.x * 8 + (tid >> 5);               // grid*8 == NN exactly
    int f = tid & 31;
    float w0f = W1[f], w1f = W1[32 + f], bf = b1[f];
    float4 an = At[node];
    int r = rsp[node];
    float di = an.z;
    float vs = fmaf(an.y, w1f, fmaf(an.x, w0f, bf));
    float acc = di * fmaxf(vs, 0.f);          // self-loop: Y[node][f]
    int beg = r >> 8, deg = r & 255;
    int e = beg;
    for (int c = deg >> 5; c > 0; --c, e += 32) {         // full 32-chunks, static
        float4 a = At[csr[e + f]];
#pragma unroll
        for (int j = 0; j < 32; ++j) {
            float a0 = __shfl(a.x, j, 32);
            float a1 = __shfl(a.y, j, 32);
            float az = __shfl(a.z, j, 32);
            float v = fmaf(a1, w1f, fmaf(a0, w0f, bf));
            acc = fmaf(az, fmaxf(v, 0.f), acc);
        }
    }
    int rem = deg & 31;
    if (rem > 0) {
        float4 a = make_float4(0.f, 0.f, 0.f, 0.f);
        if (f < rem) a = At[csr[e + f]];
        for (int j = 0; j < rem; ++j) {
            float a0 = __shfl(a.x, j, 32);
            float a1 = __shfl(a.y, j, 32);
            float az = __shfl(a.z, j, 32);
            float v = fmaf(a1, w1f, fmaf(a0, w0f, bf));
            acc = fmaf(az, fmaxf(v, 0.f), acc);
        }
    }
    accS[tid] = di * acc;                     // intra-wave transpose only
    int n0 = tid & 224;                       // group base (same wave)
    float sum = b2[f];
#pragma unroll
    for (int k = 0; k < 32; ++k) sum += accS[n0 + k] * Ws[(k << 5) + f];
    float h2 = fmaxf(sum, 0.f);
    float v = di * h2 * W3[f];
#pragma unroll
    for (int off = 16; off > 0; off >>= 1) v += __shfl_down(v, off, 32);
    if (f == 0) h3[node] = v;
}

// ---------------- width-1 gather -> out ----------------
__global__ __launch_bounds__(256) void k_gather_out(const float* __restrict__ hs,
        const int* __restrict__ rsp, const int* __restrict__ csr,
        const float* __restrict__ dinv, const float* __restrict__ bias,
        float* __restrict__ out) {
    int node = blockIdx.x * 256 + threadIdx.x;
    if (node >= NN) return;
    int r = rsp[node];
    int beg = r >> 8, end = beg + (r & 255);
    float acc = hs[node];
    int e = beg;
    for (; e + 4 <= end; e += 4) {
        int s0 = csr[e], s1 = csr[e + 1], s2 = csr[e + 2], s3 = csr[e + 3];
        acc += (hs[s0] + hs[s1]) + (hs[s2] + hs[s3]);
    }
    for (; e < end; ++e) acc += hs[csr[e]];
    out[node] = dinv[node] * acc + bias[0];
}

extern "C" void kernel_launch(void* const* d_in, const int* in_sizes, int n_in,
                              void* d_out, int out_size, void* d_ws, size_t ws_size,
                              hipStream_t stream) {
    const float* x  = (const float*)d_in[0];
    const int*   ei = (const int*)d_in[1];   // [2, NE] int32
    const float* W1 = (const float*)d_in[2];
    const float* b1 = (const float*)d_in[3];
    const float* W2 = (const float*)d_in[4];
    const float* b2 = (const float*)d_in[5];
    const float* W3 = (const float*)d_in[6];
    const float* b3 = (const float*)d_in[7];
    float* out = (float*)d_out;

    char* w = (char*)d_ws;
    float4* At    = (float4*)w; w += NN * 16;           // 16B-aligned first, 1.6 MB
    float2* xs    = (float2*)w; w += NN * 8;
    int*   cur    = (int*)w;    w += NB * 4;
    int*   rsp    = (int*)w;    w += NN * 4;
    float* dinv   = (float*)w;  w += NN * 4;
    int*   binned = (int*)w;    w += NB * CAP * 4;      // 10.8 MB
    int*   csr    = (int*)w;    w += NB * CAP * 4;      // 10.8 MB
    float* h3     = (float*)w;  w += NN * 4;

    const int G_E4K = (NE + 4095) / 4096;   // 586
    const int G_N   = (NN + 255) / 256;     // 391
    const int G_G   = (NN + 7) / 8;         // 12500 (exactly NN/8)

    hipMemsetAsync(cur, 0, NB * 4, stream);
    k_binscatter<<<G_E4K, 512, 0, stream>>>(ei, cur, binned);
    k_csr_count<<<NB, 256, 0, stream>>>(binned, cur, x, rsp, dinv, xs);
    k_csr_place<<<NB, 256, 0, stream>>>(binned, cur, rsp, xs, dinv, csr, At);
    k_gather_fly<<<G_G, 256, 0, stream>>>(At, rsp, csr, W1, b1, W2, b2, W3, h3);
    k_gather_out<<<G_N, 256, 0, stream>>>(h3, rsp, csr, dinv, b3, out);
}